// Round 1
// 135.823 us; speedup vs baseline: 1.0546x; 1.0546x over previous
//
#include <hip/hip_runtime.h>
#include <hip/hip_bf16.h>
#include <math.h>

#define NQ 9
#define NL 10
#define DIM 512
#define NCLS 10
#define B_TOT 16384

// ws layout (bytes): A bf16 [16384x512] @ 0 (16MB); BT bf16 [1024x512] @ 16MB;
// Zp f32 [4][16384][10] @ 32MB (2.62MB).
// NOTE (R13 lesson): bulk data between workgroups of ONE launch is unsafe on
// CDNA4 (per-XCD L2 non-coherent; fences insufficient for plain stores) —
// Zp crosses a kernel boundary instead.
#define A_OFF   ((size_t)0)
#define BT_OFF  ((size_t)16 << 20)
#define ZP_OFF  ((size_t)32 << 20)
#define WS_NEED (((size_t)96) << 20)

__device__ __forceinline__ float shx(float v, int m) { return __shfl_xor(v, m, 64); }

__device__ __forceinline__ int looks_bf16(const void* p, int count) {
  const unsigned short* u = (const unsigned short*)p;
  int n = count < 64 ? count : 64;
  int good = 0;
  for (int i = 0; i < n; ++i) {
    unsigned short v = u[i];
    int e = (v >> 7) & 0xFF;
    good += (e >= 100 && e <= 140) || ((v & 0x7FFF) == 0);
  }
  return good * 8 >= n * 7;
}

__device__ __forceinline__ float ld(const void* p, int i, int isbf) {
  if (isbf) return __uint_as_float(((unsigned)((const unsigned short*)p)[i]) << 16);
  return ((const float*)p)[i];
}

// ---------------- 8-amp gate helpers (verified R3; used by fallback) -------
template<int M>
__device__ __forceinline__ void rot_x(float (&sr)[8], float (&si)[8], const float* u) {
  float4 uA = *(const float4*)u;
  float4 uB = *(const float4*)(u + 4);
  bool hi = (threadIdx.x & M) != 0;
  float ar = hi ? uB.z : uA.x, ai = hi ? uB.w : uA.y;
  float br = hi ? uB.x : uA.z, bi = hi ? uB.y : uA.w;
#pragma unroll
  for (int r = 0; r < 8; ++r) {
    float pr = shx(sr[r], M), pi = shx(si[r], M);
    float nr = ar * sr[r] - ai * si[r] + br * pr - bi * pi;
    float ni = ar * si[r] + ai * sr[r] + br * pi + bi * pr;
    sr[r] = nr; si[r] = ni;
  }
}
template<int S>
__device__ __forceinline__ void rot_r(float (&sr)[8], float (&si)[8], const float* u) {
  float4 uA = *(const float4*)u;
  float4 uB = *(const float4*)(u + 4);
#pragma unroll
  for (int r0 = 0; r0 < 8; ++r0) {
    if (r0 & S) continue;
    int r1 = r0 + S;
    float a0r = sr[r0], a0i = si[r0], a1r = sr[r1], a1i = si[r1];
    sr[r0] = uA.x * a0r - uA.y * a0i + uA.z * a1r - uA.w * a1i;
    si[r0] = uA.x * a0i + uA.y * a0r + uA.z * a1i + uA.w * a1r;
    sr[r1] = uB.x * a0r - uB.y * a0i + uB.z * a1r - uB.w * a1i;
    si[r1] = uB.x * a0i + uB.y * a0r + uB.z * a1i + uB.w * a1r;
  }
}
template<int MC, int MT>
__device__ __forceinline__ void crx_ll(float (&sr)[8], float (&si)[8], const float* cs) {
  bool ctrl = (threadIdx.x & MC) != 0;
  float c = ctrl ? cs[0] : 1.0f;
  float s = ctrl ? cs[1] : 0.0f;
#pragma unroll
  for (int r = 0; r < 8; ++r) {
    float pr = shx(sr[r], MT), pi = shx(si[r], MT);
    float nr = c * sr[r] + s * pi;
    float ni = c * si[r] - s * pr;
    sr[r] = nr; si[r] = ni;
  }
}
template<int MC, int ST>
__device__ __forceinline__ void crx_lr(float (&sr)[8], float (&si)[8], const float* cs) {
  bool ctrl = (threadIdx.x & MC) != 0;
  float c = ctrl ? cs[0] : 1.0f;
  float s = ctrl ? cs[1] : 0.0f;
#pragma unroll
  for (int r0 = 0; r0 < 8; ++r0) {
    if (r0 & ST) continue;
    int r1 = r0 + ST;
    float a0r = sr[r0], a0i = si[r0], a1r = sr[r1], a1i = si[r1];
    sr[r0] = c * a0r + s * a1i;  si[r0] = c * a0i - s * a1r;
    sr[r1] = c * a1r + s * a0i;  si[r1] = c * a1i - s * a0r;
  }
}
template<int PC, int ST>
__device__ __forceinline__ void crx_rr(float (&sr)[8], float (&si)[8], const float* cs) {
  float c = cs[0], s = cs[1];
#pragma unroll
  for (int r0 = 0; r0 < 8; ++r0) {
    if (r0 & ST) continue;
    if (!((r0 >> PC) & 1)) continue;
    int r1 = r0 + ST;
    float a0r = sr[r0], a0i = si[r0], a1r = sr[r1], a1i = si[r1];
    sr[r0] = c * a0r + s * a1i;  si[r0] = c * a0i - s * a1r;
    sr[r1] = c * a1r + s * a0i;  si[r1] = c * a1i - s * a0r;
  }
}
template<int PC, int MT>
__device__ __forceinline__ void crx_rl(float (&sr)[8], float (&si)[8], const float* cs) {
  float c = cs[0], s = cs[1];
#pragma unroll
  for (int r = 0; r < 8; ++r) {
    if (!((r >> PC) & 1)) continue;
    float pr = shx(sr[r], MT), pi = shx(si[r], MT);
    float nr = c * sr[r] + s * pi;
    float ni = c * si[r] - s * pr;
    sr[r] = nr; si[r] = ni;
  }
}

__device__ __forceinline__ void build_gates(const void* rot, const void* crx,
                                            float* gU, float* gCS) {
  int tid = threadIdx.x;
  __shared__ int gflags[2];
  if (tid == 0) {
    gflags[0] = looks_bf16(rot, NL * NQ * 3);
    gflags[1] = looks_bf16(crx, NL * NQ);
  }
  __syncthreads();
  if (tid < NL * NQ) {
    int frot = gflags[0], fcrx = gflags[1];
    float phi = ld(rot, tid * 3 + 0, frot);
    float th  = ld(rot, tid * 3 + 1, frot);
    float om  = ld(rot, tid * 3 + 2, frot);
    float c = cosf(0.5f * th), s = sinf(0.5f * th);
    float a = 0.5f * (phi + om), b = 0.5f * (phi - om);
    float ca = cosf(a), sa = sinf(a), cb = cosf(b), sb = sinf(b);
    float* u = gU + tid * 8;
    u[0] =  ca * c; u[1] = -sa * c;
    u[2] = -cb * s; u[3] = -sb * s;
    u[4] =  cb * s; u[5] = -sb * s;
    u[6] =  ca * c; u[7] =  sa * c;
    float t2 = 0.5f * ld(crx, tid, fcrx);
    gCS[tid * 2 + 0] = cosf(t2);
    gCS[tid * 2 + 1] = sinf(t2);
  }
  __syncthreads();
}

__device__ __forceinline__ void run_circuit(float (&sr)[8], float (&si)[8],
                                            const float* gU, const float* gCS) {
#pragma unroll 1
  for (int n = 0; n < NL; ++n) {
    const float* U  = gU  + n * NQ * 8;
    const float* CS = gCS + n * NQ * 2;
    rot_x<32>(sr, si, U + 0 * 8);
    rot_x<16>(sr, si, U + 1 * 8);
    rot_x< 8>(sr, si, U + 2 * 8);
    rot_x< 4>(sr, si, U + 3 * 8);
    rot_x< 2>(sr, si, U + 4 * 8);
    rot_x< 1>(sr, si, U + 5 * 8);
    rot_r< 4>(sr, si, U + 6 * 8);
    rot_r< 2>(sr, si, U + 7 * 8);
    rot_r< 1>(sr, si, U + 8 * 8);
    crx_ll<32, 16>(sr, si, CS + 0 * 2);
    crx_ll<16,  8>(sr, si, CS + 1 * 2);
    crx_ll< 8,  4>(sr, si, CS + 2 * 2);
    crx_ll< 4,  2>(sr, si, CS + 3 * 2);
    crx_ll< 2,  1>(sr, si, CS + 4 * 2);
    crx_lr< 1,  4>(sr, si, CS + 5 * 2);
    crx_rr< 2,  2>(sr, si, CS + 6 * 2);
    crx_rr< 1,  1>(sr, si, CS + 7 * 2);
    crx_rl< 0, 32>(sr, si, CS + 8 * 2);
  }
}

// ---------------- 2-amp gate helpers (4-wave-per-column wbuild) ------------
template<int M>
__device__ __forceinline__ void rot_lane2(float (&sr)[2], float (&si)[2], const float* u) {
  float4 uA = *(const float4*)u;
  float4 uB = *(const float4*)(u + 4);
  bool hi = (threadIdx.x & M) != 0;
  float ar = hi ? uB.z : uA.x, ai = hi ? uB.w : uA.y;
  float br = hi ? uB.x : uA.z, bi = hi ? uB.y : uA.w;
#pragma unroll
  for (int r = 0; r < 2; ++r) {
    float pr = shx(sr[r], M), pi = shx(si[r], M);
    float nr = ar * sr[r] - ai * si[r] + br * pr - bi * pi;
    float ni = ar * si[r] + ai * sr[r] + br * pi + bi * pr;
    sr[r] = nr; si[r] = ni;
  }
}
__device__ __forceinline__ void rot_reg2(float (&sr)[2], float (&si)[2], const float* u) {
  float4 uA = *(const float4*)u;
  float4 uB = *(const float4*)(u + 4);
  float a0r = sr[0], a0i = si[0], a1r = sr[1], a1i = si[1];
  sr[0] = uA.x * a0r - uA.y * a0i + uA.z * a1r - uA.w * a1i;
  si[0] = uA.x * a0i + uA.y * a0r + uA.z * a1i + uA.w * a1r;
  sr[1] = uB.x * a0r - uB.y * a0i + uB.z * a1r - uB.w * a1i;
  si[1] = uB.x * a0i + uB.y * a0r + uB.z * a1i + uB.w * a1r;
}
__device__ __forceinline__ void crx_lane2(float (&sr)[2], float (&si)[2],
                                          float c, float s, int MT) {
#pragma unroll
  for (int r = 0; r < 2; ++r) {
    float pr = shx(sr[r], MT), pi = shx(si[r], MT);
    float nr = c * sr[r] + s * pi;
    float ni = c * si[r] - s * pr;
    sr[r] = nr; si[r] = ni;
  }
}
__device__ __forceinline__ void crx_reg2(float (&sr)[2], float (&si)[2], float c, float s) {
  float a0r = sr[0], a0i = si[0], a1r = sr[1], a1i = si[1];
  sr[0] = c * a0r + s * a1i;  si[0] = c * a0i - s * a1r;
  sr[1] = c * a1r + s * a0i;  si[1] = c * a1i - s * a0r;
}

// -------- fused prep: blocks 0..511 build one W column each (4 waves/col),
// -------- blocks 512.. cast x->bf16 and fill remaining SIMDs ---------------
__global__ __launch_bounds__(256) void prep_kernel(const void* __restrict__ x,
                                                   const void* __restrict__ rot,
                                                   const void* __restrict__ crx,
                                                   __hip_bfloat16* __restrict__ A,
                                                   __hip_bfloat16* __restrict__ BT) {
  int tid = threadIdx.x;
  if (blockIdx.x < DIM) {
    __shared__ __align__(16) float gU[NL * NQ * 8];
    __shared__ __align__(16) float gCS[NL * NQ * 2];
    __shared__ float sRe[DIM], sIm[DIM];
    build_gates(rot, crx, gU, gCS);
    int lane = tid & 63, wv = tid >> 6;
    int idx0 = wv * 128 + lane * 2;
    int k = blockIdx.x;
    float sr[2], si[2];
    sr[0] = (idx0 == k) ? 1.f : 0.f;
    sr[1] = (idx0 + 1 == k) ? 1.f : 0.f;
    si[0] = si[1] = 0.f;
#pragma unroll 1
    for (int n = 0; n < NL; ++n) {
      const float* U   = gU  + n * NQ * 8;
      const float* CS  = gCS + n * NQ * 2;
      const float* CSp = gCS + (n - 1) * NQ * 2;  // valid only for n>0
      __syncthreads();
      sRe[idx0] = sr[0]; sIm[idx0] = si[0];
      sRe[idx0 + 1] = sr[1]; sIm[idx0 + 1] = si[1];
      __syncthreads();
      {
        const float* U0 = U; const float* U1 = U + 8;
        int a = wv >> 1, b = wv & 1;
        float mr[4], mi[4];
#pragma unroll
        for (int w2 = 0; w2 < 4; ++w2) {
          int a2 = w2 >> 1, b2 = w2 & 1;
          float u0r = U0[(a * 2 + a2) * 2], u0i = U0[(a * 2 + a2) * 2 + 1];
          float u1r = U1[(b * 2 + b2) * 2], u1i = U1[(b * 2 + b2) * 2 + 1];
          mr[w2] = u0r * u1r - u0i * u1i;
          mi[w2] = u0r * u1i + u0i * u1r;
        }
        float x0r[4], x0i[4], v1r[4], v1i[4];
#pragma unroll
        for (int w2 = 0; w2 < 4; ++w2) {
          x0r[w2] = sRe[w2 * 128 + lane * 2 + 0];
          x0i[w2] = sIm[w2 * 128 + lane * 2 + 0];
          v1r[w2] = sRe[w2 * 128 + lane * 2 + 1];
          v1i[w2] = sIm[w2 * 128 + lane * 2 + 1];
        }
        float x1r[4], x1i[4];
        if (n > 0) {
          float cp = CSp[16], sp = CSp[17];
#pragma unroll
          for (int w2 = 0; w2 < 4; ++w2) {
            x1r[w2] = cp * v1r[w2] + sp * v1i[w2 ^ 2];
            x1i[w2] = cp * v1i[w2] - sp * v1r[w2 ^ 2];
          }
        } else {
#pragma unroll
          for (int w2 = 0; w2 < 4; ++w2) { x1r[w2] = v1r[w2]; x1i[w2] = v1i[w2]; }
        }
        float nr0 = 0.f, ni0 = 0.f, nr1 = 0.f, ni1 = 0.f;
#pragma unroll
        for (int w2 = 0; w2 < 4; ++w2) {
          nr0 += mr[w2] * x0r[w2] - mi[w2] * x0i[w2];
          ni0 += mr[w2] * x0i[w2] + mi[w2] * x0r[w2];
          nr1 += mr[w2] * x1r[w2] - mi[w2] * x1i[w2];
          ni1 += mr[w2] * x1i[w2] + mi[w2] * x1r[w2];
        }
        sr[0] = nr0; si[0] = ni0; sr[1] = nr1; si[1] = ni1;
      }
      rot_lane2<32>(sr, si, U + 2 * 8);
      rot_lane2<16>(sr, si, U + 3 * 8);
      rot_lane2< 8>(sr, si, U + 4 * 8);
      rot_lane2< 4>(sr, si, U + 5 * 8);
      rot_lane2< 2>(sr, si, U + 6 * 8);
      rot_lane2< 1>(sr, si, U + 7 * 8);
      rot_reg2(sr, si, U + 8 * 8);
      __syncthreads();
      sRe[idx0] = sr[0]; sIm[idx0] = si[0];
      sRe[idx0 + 1] = sr[1]; sIm[idx0 + 1] = si[1];
      __syncthreads();
      {
        float c = (wv & 2) ? CS[0] : 1.f, s = (wv & 2) ? CS[1] : 0.f;
        int p0 = (wv ^ 1) * 128 + lane * 2;
#pragma unroll
        for (int r = 0; r < 2; ++r) {
          float pr = sRe[p0 + r], pi = sIm[p0 + r];
          float nr = c * sr[r] + s * pi;
          float ni = c * si[r] - s * pr;
          sr[r] = nr; si[r] = ni;
        }
      }
      { float c = (wv & 1) ? CS[2] : 1.f, s = (wv & 1) ? CS[3] : 0.f;
        crx_lane2(sr, si, c, s, 32); }
      { bool ct = (lane & 32); crx_lane2(sr, si, ct ? CS[4] : 1.f, ct ? CS[5] : 0.f, 16); }
      { bool ct = (lane & 16); crx_lane2(sr, si, ct ? CS[6] : 1.f, ct ? CS[7] : 0.f, 8); }
      { bool ct = (lane &  8); crx_lane2(sr, si, ct ? CS[8] : 1.f, ct ? CS[9] : 0.f, 4); }
      { bool ct = (lane &  4); crx_lane2(sr, si, ct ? CS[10] : 1.f, ct ? CS[11] : 0.f, 2); }
      { bool ct = (lane &  2); crx_lane2(sr, si, ct ? CS[12] : 1.f, ct ? CS[13] : 0.f, 1); }
      { bool ct = (lane & 1); crx_reg2(sr, si, ct ? CS[14] : 1.f, ct ? CS[15] : 0.f); }
    }
    __syncthreads();
    sRe[idx0] = sr[0]; sIm[idx0] = si[0];
    sRe[idx0 + 1] = sr[1]; sIm[idx0 + 1] = si[1];
    __syncthreads();
    {
      const float* CS9 = gCS + (NL - 1) * NQ * 2;
      float c = CS9[16], s = CS9[17];
      int p1 = (wv ^ 2) * 128 + lane * 2 + 1;
      float pr = sRe[p1], pi = sIm[p1];
      float nr = c * sr[1] + s * pi;
      float ni = c * si[1] - s * pr;
      sr[1] = nr; si[1] = ni;
    }
#pragma unroll
    for (int r = 0; r < 2; ++r) {
      int j = idx0 + r;
      BT[(size_t)j * DIM + k]         = __float2bfloat16(sr[r]);  // Re W[j,k]
      BT[(size_t)(DIM + j) * DIM + k] = __float2bfloat16(si[r]);  // Im W[j,k]
    }
  } else {
    __shared__ int fx;
    if (tid == 0) fx = looks_bf16(x, B_TOT * DIM);
    __syncthreads();
    size_t i0 = ((size_t)(blockIdx.x - DIM) * 256 + tid) * 8;
    if (fx) {
      *(uint4*)(A + i0) = *(const uint4*)((const unsigned short*)x + i0);
    } else {
      const float4* src = (const float4*)((const float*)x + i0);
      float4 a = src[0], b = src[1];
      __hip_bfloat16 o[8];
      o[0] = __float2bfloat16(a.x); o[1] = __float2bfloat16(a.y);
      o[2] = __float2bfloat16(a.z); o[3] = __float2bfloat16(a.w);
      o[4] = __float2bfloat16(b.x); o[5] = __float2bfloat16(b.y);
      o[6] = __float2bfloat16(b.z); o[7] = __float2bfloat16(b.w);
      *(uint4*)(A + i0) = *(uint4*)o;
    }
  }
}

// ------- GEMM 256x256 tile, 8-wave, BK=64, counted-vmcnt pipeline ----------
// Schedule (derived from the verified 256^2 8-phase template invariants):
//   tile t in buf[t&1]; its 4 phases stage tile t+1's half-tiles in order
//   A0,B0,A1,B1; counted s_waitcnt vmcnt(4) + raw s_barrier at phase ends
//   0,1,3 (phase 2 merges into 3). Guarantee chain (vmcnt = oldest-first):
//     end-ph0: <=6 outstanding -> A1(t) landed   (needed by ph1)
//     end-ph1: <=6 outstanding -> B1(t) landed   (needed by ph2/ph3)
//     end-ph3: <=8 outstanding -> A0,B0(t+1) landed (needed by next ph0)
//   Prologue: stage tile0 (8 loads) then vmcnt(4). Epilogue drains 4->2->0.
// LDS 128KiB: [A buf0|A buf1|B buf0|B buf1] each 256x64 bf16, 16B-slot
// XOR swizzle (slot ^= row&7) applied via pre-swizzled global source
// (linear global_load_lds dest) and on the ds_read side (rule #21).
using frag8 = __attribute__((ext_vector_type(8))) short;
using frag4 = __attribute__((ext_vector_type(4))) float;

typedef __attribute__((address_space(1))) const unsigned int GU32;
typedef __attribute__((address_space(3))) unsigned int LU32;
__device__ __forceinline__ void async16(const void* g, void* l) {
  __builtin_amdgcn_global_load_lds((GU32*)g, (LU32*)l, 16, 0, 0);
}

#define VM(N) asm volatile("s_waitcnt vmcnt(" #N ")" ::: "memory")
#define BARR  do { __builtin_amdgcn_sched_barrier(0); \
                   __builtin_amdgcn_s_barrier(); \
                   __builtin_amdgcn_sched_barrier(0); } while (0)

#define STG_A(NB, T1, H) do { \
  async16(gA + ((size_t)((H) * 128) * 512 + (T1) * 64),     dA + (NB) * 16384 + (H) * 8192); \
  async16(gA + ((size_t)((H) * 128 + 8) * 512 + (T1) * 64), dA + (NB) * 16384 + (H) * 8192 + 512); \
} while (0)
#define STG_B(NB, T1, H) do { \
  async16(gB + ((size_t)((H) * 128) * 512 + (T1) * 64),     dB + (NB) * 16384 + (H) * 8192); \
  async16(gB + ((size_t)((H) * 128 + 8) * 512 + (T1) * 64), dB + (NB) * 16384 + (H) * 8192 + 512); \
} while (0)

// One phase: 12 ds_read_b128 (swizzled), stage issue, 16 MFMA under setprio.
#define PHASE(CURB, QM, QN, STG, VMC) do { \
  frag8 paf[4][2], pbf[2][2]; \
  _Pragma("unroll") \
  for (int mi = 0; mi < 4; ++mi) { \
    _Pragma("unroll") \
    for (int kk = 0; kk < 2; ++kk) \
      paf[mi][kk] = *(const frag8*)(lsm + (CURB) * 16384 + \
        ((QM) * 128 + wm * 64 + mi * 16 + r15) * 64 + \
        (((kk * 4 + quad) ^ (r15 & 7)) * 8)); \
  } \
  _Pragma("unroll") \
  for (int ni = 0; ni < 2; ++ni) { \
    _Pragma("unroll") \
    for (int kk = 0; kk < 2; ++kk) \
      pbf[ni][kk] = *(const frag8*)(lsm + 32768 + (CURB) * 16384 + \
        ((QN) * 128 + wn * 32 + ni * 16 + r15) * 64 + \
        (((kk * 4 + quad) ^ (r15 & 7)) * 8)); \
  } \
  STG; \
  __builtin_amdgcn_s_setprio(1); \
  _Pragma("unroll") \
  for (int mi = 0; mi < 4; ++mi) { \
    _Pragma("unroll") \
    for (int ni = 0; ni < 2; ++ni) { \
      acc[QM][mi][QN][ni] = __builtin_amdgcn_mfma_f32_16x16x32_bf16( \
          paf[mi][0], pbf[ni][0], acc[QM][mi][QN][ni], 0, 0, 0); \
      acc[QM][mi][QN][ni] = __builtin_amdgcn_mfma_f32_16x16x32_bf16( \
          paf[mi][1], pbf[ni][1], acc[QM][mi][QN][ni], 0, 0, 0); \
    } \
  } \
  __builtin_amdgcn_s_setprio(0); \
  VMC; \
} while (0)

__global__ __launch_bounds__(512, 2) void gemm_z_kernel(const unsigned short* __restrict__ A,
                                                        const unsigned short* __restrict__ BT,
                                                        float* __restrict__ Zp) {
  __shared__ __align__(16) unsigned short lsm[65536];  // 128 KiB
  int bid = blockIdx.x;
  int xcd = bid & 7;                 // hw round-robins consecutive bids over XCDs
  int ii = bid >> 3;                 // 0..31 per XCD
  int m0 = (xcd * 8 + (ii >> 2)) * 256;   // same-XCD blocks share A panels (L2)
  int n0 = (ii & 3) * 256;
  int tid = threadIdx.x;
  int wv = tid >> 6, lane = tid & 63;
  int wm = wv >> 2, wn = wv & 3;     // 2M x 4N wave grid; per-wave C = 128x64
  int r15 = lane & 15, quad = lane >> 4;
  int lr3 = lane >> 3;
  int scol = ((lane & 7) ^ lr3) * 8; // pre-swizzled source column (elements)
  const unsigned short* gA = A + (size_t)(m0 + wv * 16 + lr3) * 512 + scol;
  const unsigned short* gB = BT + (size_t)(n0 + wv * 16 + lr3) * 512 + scol;
  unsigned short* dA = lsm + wv * 16 * 64;           // wave-uniform LDS dests
  unsigned short* dB = lsm + 32768 + wv * 16 * 64;

  frag4 acc[2][4][2][2] = {};

  // prologue: stage tile 0 (A0,B0,A1,B1), guarantee A0,B0
  STG_A(0, 0, 0); STG_B(0, 0, 0); STG_A(0, 0, 1); STG_B(0, 0, 1);
  VM(4);
  BARR;

#pragma unroll 1
  for (int t = 0; t < 7; ++t) {
    const int cur = t & 1, nb = cur ^ 1;
    PHASE(cur, 0, 0, STG_A(nb, t + 1, 0), VM(4)); BARR;   // consumes A0,B0
    PHASE(cur, 1, 0, STG_B(nb, t + 1, 0), VM(4)); BARR;   // consumes A1,B0
    PHASE(cur, 0, 1, STG_A(nb, t + 1, 1), ;);             // consumes A0,B1
    PHASE(cur, 1, 1, STG_B(nb, t + 1, 1), VM(4)); BARR;   // consumes A1,B1
  }
  // tile 7: no staging; drain 4 -> 2 -> 0
  PHASE(1, 0, 0, ;, VM(2)); BARR;
  PHASE(1, 1, 0, ;, VM(0)); BARR;
  PHASE(1, 0, 1, ;, ;);
  PHASE(1, 1, 1, ;, ;);
  __syncthreads();

  // ---- epilogue: P = acc^2 -> LDS bf16 [256][256], same XOR slot swizzle --
#pragma unroll
  for (int qm = 0; qm < 2; ++qm)
#pragma unroll
    for (int mi = 0; mi < 4; ++mi)
#pragma unroll
      for (int qn = 0; qn < 2; ++qn)
#pragma unroll
        for (int ni = 0; ni < 2; ++ni)
#pragma unroll
          for (int rg = 0; rg < 4; ++rg) {
            float v = acc[qm][mi][qn][ni][rg];
            float p = v * v;
            int prow = qm * 128 + wm * 64 + mi * 16 + quad * 4 + rg;
            int pcol = qn * 128 + wn * 32 + ni * 16 + r15;
            int phys = (pcol >> 3) ^ (prow & 7);
            __hip_bfloat16 h = __float2bfloat16(p);
            lsm[prow * 256 + phys * 8 + (pcol & 7)] = *(unsigned short*)&h;
          }
  __syncthreads();

  // ---- second GEMM: Ztile = P . ST^T, signs computed in-register ----------
  frag8 b2[8];
#pragma unroll
  for (int kk = 0; kk < 8; ++kk) {
    union { frag8 f; unsigned short u[8]; } bb;
#pragma unroll
    for (int e = 0; e < 8; ++e) {
      int j = (n0 + kk * 32 + quad * 8 + e) & 511;
      unsigned short us;
      if (r15 < 9)      us = ((((unsigned)j) >> ((8 - r15) & 31)) & 1) ? 0xBF80 : 0x3F80;
      else if (r15 == 9) us = 0x3F80;
      else               us = 0;
      bb.u[e] = us;
    }
    b2[kk] = bb.f;
  }
  frag4 z2[2] = {};
#pragma unroll
  for (int tt = 0; tt < 2; ++tt) {
    int mt = wv + tt * 8;
#pragma unroll
    for (int kk = 0; kk < 8; ++kk) {
      frag8 a2 = *(const frag8*)(lsm + (mt * 16 + r15) * 256 +
                                 (((kk * 4 + quad) ^ (r15 & 7)) * 8));
      z2[tt] = __builtin_amdgcn_mfma_f32_16x16x32_bf16(a2, b2[kk], z2[tt], 0, 0, 0);
    }
  }
  int panel = n0 >> 8;
  if (r15 < 10) {
#pragma unroll
    for (int tt = 0; tt < 2; ++tt) {
      int mt = wv + tt * 8;
#pragma unroll
      for (int rg = 0; rg < 4; ++rg) {
        int mrow = m0 + mt * 16 + quad * 4 + rg;
        Zp[(size_t)panel * (B_TOT * 10) + (size_t)mrow * 10 + r15] = z2[tt][rg];
      }
    }
  }
}

// ------- final reduction: sum 4 panels, normalize, logits, log_softmax -----
__global__ __launch_bounds__(128) void zred_kernel(const float* __restrict__ Zp,
                                                   const void* __restrict__ fcw,
                                                   const void* __restrict__ fcb,
                                                   float* __restrict__ out) {
  __shared__ int flags[2];
  __shared__ float sW[NCLS * NQ];
  __shared__ float sB[NCLS];
  int tid = threadIdx.x;
  if (tid == 0) {
    flags[0] = looks_bf16(fcw, NCLS * NQ);
    flags[1] = looks_bf16(fcb, NCLS);
  }
  __syncthreads();
  if (tid < NCLS * NQ) sW[tid] = ld(fcw, tid, flags[0]);
  if (tid < NCLS)      sB[tid] = ld(fcb, tid, flags[1]);
  __syncthreads();
  int row = blockIdx.x * 128 + tid;
  float z[10];
#pragma unroll
  for (int q = 0; q < 10; ++q) z[q] = 0.f;
#pragma unroll
  for (int pnl = 0; pnl < 4; ++pnl) {
    const float* p = Zp + (size_t)pnl * (B_TOT * 10) + (size_t)row * 10;
#pragma unroll
    for (int q = 0; q < 10; ++q) z[q] += p[q];
  }
  float invP = 1.0f / z[9];
#pragma unroll
  for (int q = 0; q < NQ; ++q) z[q] *= invP;
  float lg[NCLS], mx = -1e30f;
#pragma unroll
  for (int k = 0; k < NCLS; ++k) {
    float t = sB[k];
#pragma unroll
    for (int q = 0; q < NQ; ++q) t += z[q] * sW[k * NQ + q];
    lg[k] = t; mx = fmaxf(mx, t);
  }
  float se = 0.f;
#pragma unroll
  for (int k = 0; k < NCLS; ++k) se += expf(lg[k] - mx);
  float lse = mx + logf(se);
#pragma unroll
  for (int k = 0; k < NCLS; ++k) out[(size_t)row * NCLS + k] = lg[k] - lse;
}

// ---------------- fallback: round-3 passing monolithic kernel --------------
__global__ __launch_bounds__(256) void qnn_kernel(
    const void* __restrict__ x, const void* __restrict__ rot,
    const void* __restrict__ crx, const void* __restrict__ fcw,
    const void* __restrict__ fcb, float* __restrict__ out) {
  __shared__ __align__(16) float gU[NL * NQ * 8];
  __shared__ __align__(16) float gCS[NL * NQ * 2];
  __shared__ int flags[3];
  int tid = threadIdx.x;
  if (tid == 0) {
    flags[0] = looks_bf16(x, B_TOT * DIM);
    flags[1] = looks_bf16(fcw, NCLS * NQ);
    flags[2] = looks_bf16(fcb, NCLS);
  }
  build_gates(rot, crx, gU, gCS);
  __syncthreads();
  int wid = (blockIdx.x * blockDim.x + tid) >> 6;
  int lane = tid & 63;
  float sr[8], si[8];
  if (flags[0]) {
    const uint4 u = *(const uint4*)((const unsigned short*)x + (size_t)wid * DIM + lane * 8);
    sr[0] = __uint_as_float(u.x << 16); sr[1] = __uint_as_float(u.x & 0xffff0000u);
    sr[2] = __uint_as_float(u.y << 16); sr[3] = __uint_as_float(u.y & 0xffff0000u);
    sr[4] = __uint_as_float(u.z << 16); sr[5] = __uint_as_float(u.z & 0xffff0000u);
    sr[6] = __uint_as_float(u.w << 16); sr[7] = __uint_as_float(u.w & 0xffff0000u);
  } else {
    const float4* xf = (const float4*)((const float*)x + (size_t)wid * DIM) + lane * 2;
    float4 a = xf[0], b = xf[1];
    sr[0] = a.x; sr[1] = a.y; sr[2] = a.z; sr[3] = a.w;
    sr[4] = b.x; sr[5] = b.y; sr[6] = b.z; sr[7] = b.w;
  }
  float nrm = 0.f;
#pragma unroll
  for (int r = 0; r < 8; ++r) { nrm += sr[r] * sr[r]; si[r] = 0.f; }
#pragma unroll
  for (int m = 1; m < 64; m <<= 1) nrm += shx(nrm, m);
  float inv = rsqrtf(nrm);
  inv = inv * (1.5f - 0.5f * nrm * inv * inv);
#pragma unroll
  for (int r = 0; r < 8; ++r) sr[r] *= inv;
  run_circuit(sr, si, gU, gCS);
  float p[8], P = 0.f;
#pragma unroll
  for (int r = 0; r < 8; ++r) { p[r] = sr[r] * sr[r] + si[r] * si[r]; P += p[r]; }
  float z[NQ];
#pragma unroll
  for (int q = 0; q < 6; ++q) z[q] = (lane & (32 >> q)) ? -P : P;
  z[6] = z[7] = z[8] = 0.f;
#pragma unroll
  for (int r = 0; r < 8; ++r) {
    z[6] += (r & 4) ? -p[r] : p[r];
    z[7] += (r & 2) ? -p[r] : p[r];
    z[8] += (r & 1) ? -p[r] : p[r];
  }
#pragma unroll
  for (int m = 1; m < 64; m <<= 1) {
#pragma unroll
    for (int q = 0; q < NQ; ++q) z[q] += shx(z[q], m);
  }
  int ffw = flags[1], ffb = flags[2];
  float lg[NCLS], mx = -1e30f;
#pragma unroll
  for (int k = 0; k < NCLS; ++k) {
    float t = ld(fcb, k, ffb);
#pragma unroll
    for (int q = 0; q < NQ; ++q) t += z[q] * ld(fcw, k * NQ + q, ffw);
    lg[k] = t; mx = fmaxf(mx, t);
  }
  float se = 0.f;
#pragma unroll
  for (int k = 0; k < NCLS; ++k) se += expf(lg[k] - mx);
  float lse = mx + logf(se);
  if (lane < NCLS) out[(size_t)wid * NCLS + lane] = lg[lane] - lse;
}

extern "C" void kernel_launch(void* const* d_in, const int* in_sizes, int n_in,
                              void* d_out, int out_size, void* d_ws, size_t ws_size,
                              hipStream_t stream) {
  const void* x   = d_in[0];
  const void* rot = d_in[1];
  const void* crx = d_in[2];
  const void* fcw = d_in[3];
  const void* fcb = d_in[4];
  float* out = (float*)d_out;
  if (ws_size >= WS_NEED) {
    __hip_bfloat16* A  = (__hip_bfloat16*)((char*)d_ws + A_OFF);
    __hip_bfloat16* BT = (__hip_bfloat16*)((char*)d_ws + BT_OFF);
    float*          Zp = (float*)((char*)d_ws + ZP_OFF);
    prep_kernel<<<DIM + (B_TOT * DIM) / (256 * 8), 256, 0, stream>>>(x, rot, crx, A, BT);
    gemm_z_kernel<<<(B_TOT / 256) * (1024 / 256), 512, 0, stream>>>(
        (const unsigned short*)A, (const unsigned short*)BT, Zp);
    zred_kernel<<<B_TOT / 128, 128, 0, stream>>>(Zp, fcw, fcb, out);
  } else {
    qnn_kernel<<<(B_TOT * 64) / 256, 256, 0, stream>>>(x, rot, crx, fcw, fcb, out);
  }
}